// Round 9
// baseline (83.148 us; speedup 1.0000x reference)
//
#include <hip/hip_runtime.h>
#include <hip/hip_bf16.h>
#include <hip/hip_fp8.h>
#include <stdint.h>

// VQ: z (32,256,32,32) f32 NCHW, codebook (1024,256) f32
// out: z_q (8388608 f32 NCHW) + commit_loss (1 f32 at out[8388608])
//
// R9 = R8 with the fp8 cvt builtin fixed (hi-select must be a constant =>
// template<bool HI>). Theory unchanged:
// Kill the codebook L2-streaming wall (R2-R7: 512MB L2 demand vs 34.5TB/s
// ceiling => latency-amplified ~60us floor). Codebook quarter (256 codes)
// LDS-RESIDENT in fp8 e4m3 (pre-scaled x-512 => +-0.5, well inside e4m3;
// argmin flips bounded: codes in +-1e-3 so zq moves <=2e-3 << 2.5e-2).
// k1: 512 blocks (4 quarters x 128 pos-groups, q-major => co-XCD z sharing),
// 512 thr, 64KB LDS, 2 blocks/CU = 4 waves/SIMD. Main loop: LDS reads + MFMA
// only - no global, no barriers. Encoded argmin (S & ~0x3FF)|code -> penc.
// k2: 4-way merge + gather + NCHW write (proven epilogue). k3: loss reduce.

#define WS_CN    0                 // 1024 f32
#define WS_CB    4096              // 256 KB fp8 frags
#define WS_PENC  266240            // 4*32768 f32 = 512 KB
#define WS_PART2 790528            // 128 f32 (z^2 partials)
#define WS_PART  791040            // 512 f32 (minS partials)

typedef float f32x4 __attribute__((ext_vector_type(4)));
typedef long  i64;
typedef long  l64x2 __attribute__((ext_vector_type(2)));

template <bool HI>
static __device__ __forceinline__ unsigned pk2(float a, float b, unsigned old) {
#if __has_builtin(__builtin_amdgcn_cvt_pk_fp8_f32)
    return (unsigned)__builtin_amdgcn_cvt_pk_fp8_f32(a, b, (int)old, HI);
#else
    __hip_fp8_e4m3 qa(a), qb(b);
    unsigned w = (unsigned)qa.__x | ((unsigned)qb.__x << 8);
    return HI ? ((old & 0x0000FFFFu) | (w << 16)) : ((old & 0xFFFF0000u) | w);
#endif
}

// ---------------- K0: cnorm*256 + (-512*codebook) fp8 fragment-ordered ----------------
// frag unit (16B) = [q][chunk16][kp4][lane64]; lane = g4*16 + r16 holds
// A[row=r16][k = ks*32 + g4*8 + j]; bytes (ks&1)*8 + j, ks = 2kp, 2kp+1.
__global__ __launch_bounds__(64) void k0_prep(const float* __restrict__ cb,
                                              float* __restrict__ cn256,
                                              unsigned char* __restrict__ cbf8) {
    const int code = blockIdx.x;
    const int l = threadIdx.x;
    const float4 v = ((const float4*)cb)[code * 64 + l];   // k = 4l..4l+3
    float nrm = v.x * v.x + v.y * v.y + v.z * v.z + v.w * v.w;
    #pragma unroll
    for (int off = 1; off < 64; off <<= 1) nrm += __shfl_xor(nrm, off);
    if (l == 0) cn256[code] = 256.f * nrm;
    unsigned u = pk2<false>(-512.f * v.x, -512.f * v.y, 0u);
    u = pk2<true>(-512.f * v.z, -512.f * v.w, u);
    const int q = code >> 8, chunk = (code >> 4) & 15, r16 = code & 15;
    const int ks = l >> 3, kp = l >> 4, g4 = (l >> 1) & 3;
    const int lane = g4 * 16 + r16;
    const int byteoff = q * 65536 + ((chunk * 4 + kp) * 64 + lane) * 16
                      + (ks & 1) * 8 + (l & 1) * 4;
    *(unsigned*)(cbf8 + byteoff) = u;
}

// ---------------- K1: per-quarter distances + encoded argmin ----------------
__global__ __launch_bounds__(512, 4) void k1_main(const float* __restrict__ z,
                                                  const unsigned char* __restrict__ cbf8,
                                                  const float* __restrict__ cn256,
                                                  float* __restrict__ penc,
                                                  float* __restrict__ part2) {
    __shared__ __align__(16) unsigned char lds[65536];
    const int t = threadIdx.x, w = t >> 6, l = t & 63;
    const int col = l & 15, g4 = l >> 4, gc4 = g4 * 4;
    const int b = blockIdx.x, q = b >> 7, grp = b & 127;   // q-major: co-XCD per grp
    const int img = grp >> 2, hw0 = (grp & 3) << 8;        // 256 pos per group

    // stage quarter codebook (64 KB) -> LDS, linear, global_load_lds x16B
    {
        const unsigned char* src = cbf8 + q * 65536;
        #pragma unroll
        for (int i = 0; i < 8; ++i) {
            const int off = i * 8192 + w * 1024;
            __builtin_amdgcn_global_load_lds(
                (const __attribute__((address_space(1))) unsigned*)(src + off + l * 16),
                (__attribute__((address_space(3))) unsigned*)(lds + off), 16, 0, 0);
        }
    }

    // z -> fp8 B-frags (32 pos per wave) + z^2 (f32)
    const float* zp = z + img * 262144 + hw0 + w * 32;
    float z2 = 0.f;
    i64 zf[2][8];
    #pragma unroll
    for (int pf = 0; pf < 2; ++pf) {
        const int p = pf * 16 + col;
        #pragma unroll
        for (int ks = 0; ks < 8; ++ks) {
            const float* s0 = zp + (ks * 32 + g4 * 8) * 1024 + p;
            float v0 = s0[0], v1 = s0[1024], v2 = s0[2048], v3 = s0[3072];
            float v4 = s0[4096], v5 = s0[5120], v6 = s0[6144], v7 = s0[7168];
            z2 += v0*v0 + v1*v1 + v2*v2 + v3*v3 + v4*v4 + v5*v5 + v6*v6 + v7*v7;
            unsigned lo = pk2<false>(v0, v1, 0u); lo = pk2<true>(v2, v3, lo);
            unsigned hi = pk2<false>(v4, v5, 0u); hi = pk2<true>(v6, v7, hi);
            zf[pf][ks] = (i64)(((unsigned long)hi << 32) | (unsigned long)lo);
        }
    }
    __syncthreads();   // staging (and z loads) complete

    float menc0 = __builtin_bit_cast(float, 0x7F7FFC00u);
    float menc1 = __builtin_bit_cast(float, 0x7F7FFC00u);

    i64 A0[8], A1[8];
#define LDA(DST, c) do {                                                         \
    _Pragma("unroll") for (int kp = 0; kp < 4; ++kp) {                           \
        l64x2 u = *(const l64x2*)(lds + (((c) * 4 + kp) * 64 + l) * 16);         \
        DST[2 * kp] = u.x; DST[2 * kp + 1] = u.y;                                \
    }                                                                            \
} while (0)
#define BODY(CUR, NXT, c) do {                                                   \
    if ((c) + 1 < 16) LDA(NXT, (c) + 1);                                         \
    f32x4 a0 = {0.f,0.f,0.f,0.f}, a1 = {0.f,0.f,0.f,0.f};                        \
    _Pragma("unroll") for (int ks = 0; ks < 8; ++ks) {                           \
        a0 = __builtin_amdgcn_mfma_f32_16x16x32_fp8_fp8(CUR[ks], zf[0][ks], a0, 0, 0, 0); \
        a1 = __builtin_amdgcn_mfma_f32_16x16x32_fp8_fp8(CUR[ks], zf[1][ks], a1, 0, 0, 0); \
    }                                                                            \
    {                                                                            \
        const f32x4 cn = *(const f32x4*)(cn256 + q * 256 + (c) * 16 + gc4);      \
        _Pragma("unroll") for (int r = 0; r < 4; ++r) {                          \
            const unsigned code0 = (unsigned)(q * 256 + (c) * 16 + gc4 + r);     \
            float s; unsigned e;                                                 \
            s = a0[r] + cn[r];                                                   \
            e = (__builtin_bit_cast(unsigned, s) & 0xFFFFFC00u) | code0;         \
            menc0 = fminf(menc0, __builtin_bit_cast(float, e));                  \
            s = a1[r] + cn[r];                                                   \
            e = (__builtin_bit_cast(unsigned, s) & 0xFFFFFC00u) | code0;         \
            menc1 = fminf(menc1, __builtin_bit_cast(float, e));                  \
        }                                                                        \
    }                                                                            \
} while (0)

    LDA(A0, 0);
    #pragma unroll 1
    for (int c2 = 0; c2 < 16; c2 += 2) {
        BODY(A0, A1, c2);
        BODY(A1, A0, c2 + 1);
    }
#undef BODY
#undef LDA

    // merge across the 4 g-groups sharing each pos column
    menc0 = fminf(menc0, __shfl_xor(menc0, 16));
    menc0 = fminf(menc0, __shfl_xor(menc0, 32));
    menc1 = fminf(menc1, __shfl_xor(menc1, 16));
    menc1 = fminf(menc1, __shfl_xor(menc1, 32));
    const int posbase = img * 1024 + hw0 + w * 32;
    if (l < 16) {
        penc[q * 32768 + posbase + l]      = menc0;
        penc[q * 32768 + posbase + 16 + l] = menc1;
    }

    // z^2 partial (identical across quarters -> only q==0 contributes)
    #pragma unroll
    for (int off = 1; off < 64; off <<= 1) z2 += __shfl_xor(z2, off);
    __syncthreads();                      // codebook reads done; reuse lds head
    float* red = (float*)lds;
    if (l == 0) red[w] = z2;
    __syncthreads();
    if (t == 0 && q == 0) {
        float s = 0.f;
        #pragma unroll
        for (int i = 0; i < 8; ++i) s += red[i];
        part2[grp] = s;
    }
}

// ---------------- K2: 4-way merge + z_q gather/transpose/write + minS partial ----------------
__global__ __launch_bounds__(256) void k2_out(const float* __restrict__ cbf,
                                              const float* __restrict__ penc,
                                              float* __restrict__ out,
                                              float* __restrict__ part) {
    __shared__ __align__(16) float zqbuf[32 * 260];
    __shared__ unsigned idxl[64];
    const int t = threadIdx.x, b = blockIdx.x;
    const int pos0 = b * 64, img = pos0 >> 10, hw0 = pos0 & 1023;

    if (t < 64) {
        const int pos = pos0 + t;
        const float e = fminf(fminf(penc[pos], penc[32768 + pos]),
                              fminf(penc[65536 + pos], penc[98304 + pos]));
        const unsigned eu = __builtin_bit_cast(unsigned, e);
        idxl[t] = eu & 0x3FFu;
        float myS = __builtin_bit_cast(float, eu & 0xFFFFFC00u);
        #pragma unroll
        for (int off = 1; off < 64; off <<= 1) myS += __shfl_xor(myS, off);
        if (t == 0) part[b] = myS * (1.f / 256.f);
    }

    const float4* cb4 = (const float4*)cbf;
    for (int h = 0; h < 2; ++h) {
        __syncthreads();
        #pragma unroll
        for (int i = 0; i < 8; ++i) {
            const int flat = i * 256 + t;        // [0,2048)
            const int p = flat >> 6;             // row 0..31
            const int qq = flat & 63;            // float4 index
            const unsigned code = idxl[h * 32 + p];
            *(float4*)&zqbuf[p * 260 + qq * 4] = cb4[code * 64 + qq];
        }
        __syncthreads();
        const int p = t & 31, c0 = t >> 5;       // c0 0..7
        float* ob = out + img * 262144 + hw0 + h * 32 + p;
        #pragma unroll
        for (int cc = 0; cc < 32; ++cc) {
            const int ch = c0 + cc * 8;
            ob[ch * 1024] = zqbuf[p * 260 + ch];
        }
    }
}

// ---------------- K3: deterministic loss reduce ----------------
__global__ __launch_bounds__(256) void k3_red(const float* __restrict__ part2,
                                              const float* __restrict__ part,
                                              float* __restrict__ out) {
    __shared__ float red[256];
    const int t = threadIdx.x;
    float v = part[t] + part[t + 256];
    if (t < 128) v += part2[t];
    red[t] = v;
    __syncthreads();
    #pragma unroll
    for (int off = 128; off > 0; off >>= 1) {
        if (t < off) red[t] += red[t + off];
        __syncthreads();
    }
    if (t == 0) out[8388608] = 1.25f * red[0] / 8388608.f;
}

extern "C" void kernel_launch(void* const* d_in, const int* in_sizes, int n_in,
                              void* d_out, int out_size, void* d_ws, size_t ws_size,
                              hipStream_t stream) {
    const float* z  = (const float*)d_in[0];
    const float* cb = (const float*)d_in[1];
    float* out = (float*)d_out;
    unsigned char* ws = (unsigned char*)d_ws;
    float* cn256 = (float*)(ws + WS_CN);
    unsigned char* cbf8 = ws + WS_CB;
    float* penc  = (float*)(ws + WS_PENC);
    float* part2 = (float*)(ws + WS_PART2);
    float* part  = (float*)(ws + WS_PART);

    hipLaunchKernelGGL(k0_prep, dim3(1024), dim3(64), 0, stream, cb, cn256, cbf8);
    hipLaunchKernelGGL(k1_main, dim3(512), dim3(512), 0, stream, z, cbf8, cn256, penc, part2);
    hipLaunchKernelGGL(k2_out,  dim3(512), dim3(256), 0, stream, cb, penc, out, part);
    hipLaunchKernelGGL(k3_red,  dim3(1), dim3(256), 0, stream, part2, part, out);
}

// Round 10
// 45.373 us; speedup vs baseline: 1.8325x; 1.8325x over previous
//
#include <hip/hip_runtime.h>
#include <hip/hip_bf16.h>
#include <hip/hip_fp8.h>
#include <stdint.h>

// VQ: z (32,256,32,32) f32 NCHW, codebook (1024,256) f32
// out: z_q (8388608 f32 NCHW) + commit_loss (1 f32 at out[8388608])
//
// R10 = R9 with the REAL register fix: plain __launch_bounds__(512).
// Empirical launch_bounds semantics on this hipcc (R3: (512,2)->128 VGPR,
// R9: (512,4)->64 VGPR): 2nd arg ~ blocks/CU, cap = 2048/(waves/CU).
// R9's 64-VGPR cap spilled everything (FETCH 80MB vs 35 ideal) and k1
// stayed at 68us. Natural allocation (~100-150 VGPR) -> 2 blocks/CU.
//
// Structure (unchanged): codebook quarter (256 codes) LDS-RESIDENT in fp8
// e4m3 (pre-scaled x-512); k1: 512 blocks (4 quarters x 128 pos-groups,
// q-major), 512 thr, 64KB LDS. Main loop: LDS reads + fp8 MFMA only.
// Encoded argmin (S & ~0x3FF)|code -> penc. k2: 4-way merge + gather +
// NCHW write. k3: loss reduce. absmax 1.95e-3 with fp8 (R9, passed).

#define WS_CN    0                 // 1024 f32
#define WS_CB    4096              // 256 KB fp8 frags
#define WS_PENC  266240            // 4*32768 f32 = 512 KB
#define WS_PART2 790528            // 128 f32 (z^2 partials)
#define WS_PART  791040            // 512 f32 (minS partials)

typedef float f32x4 __attribute__((ext_vector_type(4)));
typedef long  i64;
typedef long  l64x2 __attribute__((ext_vector_type(2)));

template <bool HI>
static __device__ __forceinline__ unsigned pk2(float a, float b, unsigned old) {
#if __has_builtin(__builtin_amdgcn_cvt_pk_fp8_f32)
    return (unsigned)__builtin_amdgcn_cvt_pk_fp8_f32(a, b, (int)old, HI);
#else
    __hip_fp8_e4m3 qa(a), qb(b);
    unsigned w = (unsigned)qa.__x | ((unsigned)qb.__x << 8);
    return HI ? ((old & 0x0000FFFFu) | (w << 16)) : ((old & 0xFFFF0000u) | w);
#endif
}

// ---------------- K0: cnorm*256 + (-512*codebook) fp8 fragment-ordered ----------------
// frag unit (16B) = [q][chunk16][kp4][lane64]; lane = g4*16 + r16 holds
// A[row=r16][k = ks*32 + g4*8 + j]; bytes (ks&1)*8 + j, ks = 2kp, 2kp+1.
__global__ __launch_bounds__(64) void k0_prep(const float* __restrict__ cb,
                                              float* __restrict__ cn256,
                                              unsigned char* __restrict__ cbf8) {
    const int code = blockIdx.x;
    const int l = threadIdx.x;
    const float4 v = ((const float4*)cb)[code * 64 + l];   // k = 4l..4l+3
    float nrm = v.x * v.x + v.y * v.y + v.z * v.z + v.w * v.w;
    #pragma unroll
    for (int off = 1; off < 64; off <<= 1) nrm += __shfl_xor(nrm, off);
    if (l == 0) cn256[code] = 256.f * nrm;
    unsigned u = pk2<false>(-512.f * v.x, -512.f * v.y, 0u);
    u = pk2<true>(-512.f * v.z, -512.f * v.w, u);
    const int q = code >> 8, chunk = (code >> 4) & 15, r16 = code & 15;
    const int ks = l >> 3, kp = l >> 4, g4 = (l >> 1) & 3;
    const int lane = g4 * 16 + r16;
    const int byteoff = q * 65536 + ((chunk * 4 + kp) * 64 + lane) * 16
                      + (ks & 1) * 8 + (l & 1) * 4;
    *(unsigned*)(cbf8 + byteoff) = u;
}

// ---------------- K1: per-quarter distances + encoded argmin ----------------
__global__ __launch_bounds__(512) void k1_main(const float* __restrict__ z,
                                               const unsigned char* __restrict__ cbf8,
                                               const float* __restrict__ cn256,
                                               float* __restrict__ penc,
                                               float* __restrict__ part2) {
    __shared__ __align__(16) unsigned char lds[65536];
    const int t = threadIdx.x, w = t >> 6, l = t & 63;
    const int col = l & 15, g4 = l >> 4, gc4 = g4 * 4;
    const int b = blockIdx.x, q = b >> 7, grp = b & 127;   // q-major: co-XCD per grp
    const int img = grp >> 2, hw0 = (grp & 3) << 8;        // 256 pos per group

    // stage quarter codebook (64 KB) -> LDS, linear, global_load_lds x16B
    {
        const unsigned char* src = cbf8 + q * 65536;
        #pragma unroll
        for (int i = 0; i < 8; ++i) {
            const int off = i * 8192 + w * 1024;
            __builtin_amdgcn_global_load_lds(
                (const __attribute__((address_space(1))) unsigned*)(src + off + l * 16),
                (__attribute__((address_space(3))) unsigned*)(lds + off), 16, 0, 0);
        }
    }

    // z -> fp8 B-frags (32 pos per wave) + z^2 (f32)
    const float* zp = z + img * 262144 + hw0 + w * 32;
    float z2 = 0.f;
    i64 zf[2][8];
    #pragma unroll
    for (int pf = 0; pf < 2; ++pf) {
        const int p = pf * 16 + col;
        #pragma unroll
        for (int ks = 0; ks < 8; ++ks) {
            const float* s0 = zp + (ks * 32 + g4 * 8) * 1024 + p;
            float v0 = s0[0], v1 = s0[1024], v2 = s0[2048], v3 = s0[3072];
            float v4 = s0[4096], v5 = s0[5120], v6 = s0[6144], v7 = s0[7168];
            z2 += v0*v0 + v1*v1 + v2*v2 + v3*v3 + v4*v4 + v5*v5 + v6*v6 + v7*v7;
            unsigned lo = pk2<false>(v0, v1, 0u); lo = pk2<true>(v2, v3, lo);
            unsigned hi = pk2<false>(v4, v5, 0u); hi = pk2<true>(v6, v7, hi);
            zf[pf][ks] = (i64)(((unsigned long)hi << 32) | (unsigned long)lo);
        }
    }
    __syncthreads();   // staging (and z loads) complete

    float menc0 = __builtin_bit_cast(float, 0x7F7FFC00u);
    float menc1 = __builtin_bit_cast(float, 0x7F7FFC00u);

    i64 A0[8], A1[8];
#define LDA(DST, c) do {                                                         \
    _Pragma("unroll") for (int kp = 0; kp < 4; ++kp) {                           \
        l64x2 u = *(const l64x2*)(lds + (((c) * 4 + kp) * 64 + l) * 16);         \
        DST[2 * kp] = u.x; DST[2 * kp + 1] = u.y;                                \
    }                                                                            \
} while (0)
#define BODY(CUR, NXT, c) do {                                                   \
    if ((c) + 1 < 16) LDA(NXT, (c) + 1);                                         \
    f32x4 a0 = {0.f,0.f,0.f,0.f}, a1 = {0.f,0.f,0.f,0.f};                        \
    _Pragma("unroll") for (int ks = 0; ks < 8; ++ks) {                           \
        a0 = __builtin_amdgcn_mfma_f32_16x16x32_fp8_fp8(CUR[ks], zf[0][ks], a0, 0, 0, 0); \
        a1 = __builtin_amdgcn_mfma_f32_16x16x32_fp8_fp8(CUR[ks], zf[1][ks], a1, 0, 0, 0); \
    }                                                                            \
    {                                                                            \
        const f32x4 cn = *(const f32x4*)(cn256 + q * 256 + (c) * 16 + gc4);      \
        _Pragma("unroll") for (int r = 0; r < 4; ++r) {                          \
            const unsigned code0 = (unsigned)(q * 256 + (c) * 16 + gc4 + r);     \
            float s; unsigned e;                                                 \
            s = a0[r] + cn[r];                                                   \
            e = (__builtin_bit_cast(unsigned, s) & 0xFFFFFC00u) | code0;         \
            menc0 = fminf(menc0, __builtin_bit_cast(float, e));                  \
            s = a1[r] + cn[r];                                                   \
            e = (__builtin_bit_cast(unsigned, s) & 0xFFFFFC00u) | code0;         \
            menc1 = fminf(menc1, __builtin_bit_cast(float, e));                  \
        }                                                                        \
    }                                                                            \
} while (0)

    LDA(A0, 0);
    #pragma unroll 1
    for (int c2 = 0; c2 < 16; c2 += 2) {
        BODY(A0, A1, c2);
        BODY(A1, A0, c2 + 1);
    }
#undef BODY
#undef LDA

    // merge across the 4 g-groups sharing each pos column
    menc0 = fminf(menc0, __shfl_xor(menc0, 16));
    menc0 = fminf(menc0, __shfl_xor(menc0, 32));
    menc1 = fminf(menc1, __shfl_xor(menc1, 16));
    menc1 = fminf(menc1, __shfl_xor(menc1, 32));
    const int posbase = img * 1024 + hw0 + w * 32;
    if (l < 16) {
        penc[q * 32768 + posbase + l]      = menc0;
        penc[q * 32768 + posbase + 16 + l] = menc1;
    }

    // z^2 partial (identical across quarters -> only q==0 contributes)
    #pragma unroll
    for (int off = 1; off < 64; off <<= 1) z2 += __shfl_xor(z2, off);
    __syncthreads();                      // codebook reads done; reuse lds head
    float* red = (float*)lds;
    if (l == 0) red[w] = z2;
    __syncthreads();
    if (t == 0 && q == 0) {
        float s = 0.f;
        #pragma unroll
        for (int i = 0; i < 8; ++i) s += red[i];
        part2[grp] = s;
    }
}

// ---------------- K2: 4-way merge + z_q gather/transpose/write + minS partial ----------------
__global__ __launch_bounds__(256) void k2_out(const float* __restrict__ cbf,
                                              const float* __restrict__ penc,
                                              float* __restrict__ out,
                                              float* __restrict__ part) {
    __shared__ __align__(16) float zqbuf[32 * 260];
    __shared__ unsigned idxl[64];
    const int t = threadIdx.x, b = blockIdx.x;
    const int pos0 = b * 64, img = pos0 >> 10, hw0 = pos0 & 1023;

    if (t < 64) {
        const int pos = pos0 + t;
        const float e = fminf(fminf(penc[pos], penc[32768 + pos]),
                              fminf(penc[65536 + pos], penc[98304 + pos]));
        const unsigned eu = __builtin_bit_cast(unsigned, e);
        idxl[t] = eu & 0x3FFu;
        float myS = __builtin_bit_cast(float, eu & 0xFFFFFC00u);
        #pragma unroll
        for (int off = 1; off < 64; off <<= 1) myS += __shfl_xor(myS, off);
        if (t == 0) part[b] = myS * (1.f / 256.f);
    }

    const float4* cb4 = (const float4*)cbf;
    for (int h = 0; h < 2; ++h) {
        __syncthreads();
        #pragma unroll
        for (int i = 0; i < 8; ++i) {
            const int flat = i * 256 + t;        // [0,2048)
            const int p = flat >> 6;             // row 0..31
            const int qq = flat & 63;            // float4 index
            const unsigned code = idxl[h * 32 + p];
            *(float4*)&zqbuf[p * 260 + qq * 4] = cb4[code * 64 + qq];
        }
        __syncthreads();
        const int p = t & 31, c0 = t >> 5;       // c0 0..7
        float* ob = out + img * 262144 + hw0 + h * 32 + p;
        #pragma unroll
        for (int cc = 0; cc < 32; ++cc) {
            const int ch = c0 + cc * 8;
            ob[ch * 1024] = zqbuf[p * 260 + ch];
        }
    }
}

// ---------------- K3: deterministic loss reduce ----------------
__global__ __launch_bounds__(256) void k3_red(const float* __restrict__ part2,
                                              const float* __restrict__ part,
                                              float* __restrict__ out) {
    __shared__ float red[256];
    const int t = threadIdx.x;
    float v = part[t] + part[t + 256];
    if (t < 128) v += part2[t];
    red[t] = v;
    __syncthreads();
    #pragma unroll
    for (int off = 128; off > 0; off >>= 1) {
        if (t < off) red[t] += red[t + off];
        __syncthreads();
    }
    if (t == 0) out[8388608] = 1.25f * red[0] / 8388608.f;
}

extern "C" void kernel_launch(void* const* d_in, const int* in_sizes, int n_in,
                              void* d_out, int out_size, void* d_ws, size_t ws_size,
                              hipStream_t stream) {
    const float* z  = (const float*)d_in[0];
    const float* cb = (const float*)d_in[1];
    float* out = (float*)d_out;
    unsigned char* ws = (unsigned char*)d_ws;
    float* cn256 = (float*)(ws + WS_CN);
    unsigned char* cbf8 = ws + WS_CB;
    float* penc  = (float*)(ws + WS_PENC);
    float* part2 = (float*)(ws + WS_PART2);
    float* part  = (float*)(ws + WS_PART);

    hipLaunchKernelGGL(k0_prep, dim3(1024), dim3(64), 0, stream, cb, cn256, cbf8);
    hipLaunchKernelGGL(k1_main, dim3(512), dim3(512), 0, stream, z, cbf8, cn256, penc, part2);
    hipLaunchKernelGGL(k2_out,  dim3(512), dim3(256), 0, stream, cb, penc, out, part);
    hipLaunchKernelGGL(k3_red,  dim3(1), dim3(256), 0, stream, part2, part, out);
}